// Round 19
// baseline (680.631 us; speedup 1.0000x reference)
//
#include <hip/hip_runtime.h>
#include <hip/hip_bf16.h>

// MoE head: router(top2 of 8) -> compact -> GEMM1+GELU -> GEMM2(split-K x4) -> combine+residual+LN
// R19: k_pre transpose restaged via ASYNC global_load_lds (DMA queue does the latency hiding,
//      no VGPR round-trip): 64 GLD16/block stage a 128x128 fp32 tile into 64KB LDS, one
//      vmcnt(0)+barrier, column-gather (2-lane/bank free) -> convert -> NT 128B-segment stores.
//      Tests the last untried streaming mechanism against the ~2.4TB/s weight-stream cap.
//      Router/GEMMs/place/combine byte-identical to R18.

typedef unsigned short u16;
typedef unsigned int u32;
typedef __attribute__((ext_vector_type(4))) float f32x4;
typedef __attribute__((ext_vector_type(8))) short s16x8;
typedef __attribute__((ext_vector_type(4))) unsigned short u16x4;
typedef __attribute__((ext_vector_type(8))) unsigned short u16x8;

#define GLD16(gp, lp) __builtin_amdgcn_global_load_lds( \
    (const __attribute__((address_space(1))) void*)(gp), \
    (__attribute__((address_space(3))) void*)(lp), 16, 0, 0)

__device__ __forceinline__ u16 f2bf(float f) {
    union { float f; u32 u; } v; v.f = f;
    u32 u = v.u;
    return (u16)((u + 0x7fffu + ((u >> 16) & 1u)) >> 16);
}
__device__ __forceinline__ float bf2f(u16 h) {
    union { u32 u; float f; } v; v.u = ((u32)h) << 16; return v.f;
}

// fast GELU: v * sigmoid(1.59577v + 0.0713548v^3)
__device__ __forceinline__ float gelu_f(float v) {
    const float u = v * (0.7978845608f + 0.0356774081f * v * v);
    const float t = __expf(-2.0f * u);
    return v * __builtin_amdgcn_rcpf(1.0f + t);
}

// ---------------- K0: zero counts+cursors (16 ints) ----------------
__global__ void k_init(int* cc) { if (threadIdx.x < 16) cc[threadIdx.x] = 0; }

#define VMCNT4 asm volatile("s_waitcnt vmcnt(4)" ::: "memory")
#define VMCNT0 asm volatile("s_waitcnt vmcnt(0)" ::: "memory")
#define BAR __builtin_amdgcn_s_barrier()

// ---------------- K1: fused router + W1/W2 transpose-convert (5120 blocks) ----------------
// blocks 0..1023: router; 1024..3071: W1 tiles; 3072..5119: W2 tiles.
// transp: SRC [K][N] f32 -> DST [N][K] bf16, 128k x 128n per block.
// Stage tile via async GLD16 (2 rows / instr, 16 / wave); column-gather + NT stores.
__global__ __launch_bounds__(256) void k_pre(
    const float* __restrict__ x, const float* __restrict__ rw, const float* __restrict__ rb,
    u16* __restrict__ xb, int* __restrict__ eidx, float* __restrict__ wgt, int* __restrict__ counts,
    const float* __restrict__ W1, u16* __restrict__ W1t,
    const float* __restrict__ W2, u16* __restrict__ W2t)
{
    __shared__ float tl[128 * 128];   // 64KB fp32 tile (transpose blocks only)
    const int id = blockIdx.x;
    const int tid = threadIdx.x;

    if (id >= 1024) {
        const float* s; u16* d; int K, N, k0, n0;
        if (id < 3072) {
            const int id2 = id - 1024;          // W1: 256 tiles/e (8 kt x 32 nt)
            const int e = id2 >> 8, rem = id2 & 255;
            K = 1024; N = 4096;
            k0 = (rem >> 5) * 128; n0 = (rem & 31) * 128;
            s = W1 + (size_t)e * 1024 * 4096; d = W1t + (size_t)e * 1024 * 4096;
        } else {
            const int id3 = id - 3072;          // W2: 256 tiles/e (32 kt x 8 nt)
            const int e = id3 >> 8, rem = id3 & 255;
            K = 4096; N = 1024;
            k0 = (rem >> 3) * 128; n0 = (rem & 7) * 128;
            s = W2 + (size_t)e * 4096 * 1024; d = W2t + (size_t)e * 1024 * 4096;
        }

        const int wav = tid >> 6, lane = tid & 63;
        // PHASE 1: async DMA — wave w stages rows w*32 .. w*32+31, 2 rows per GLD16.
        // src per-lane: row r + (lane>>5), 16B chunk (lane&31); dest wave-uniform row base.
        {
            const int lrow = lane >> 5, lcol = (lane & 31) * 4;
            #pragma unroll
            for (int i = 0; i < 16; ++i) {
                const int r = wav * 32 + i * 2;
                const float* src = s + (size_t)(k0 + r + lrow) * N + n0 + lcol;
                GLD16(src, (char*)tl + (size_t)r * 512);
            }
        }
        VMCNT0;
        BAR;
        // PHASE 2: column gather (n = tid>>1, k-half = tid&1): 64 scalar LDS reads
        // (2 lanes/bank = free), convert, 8 x 16B NT stores (128B/thread contiguous).
        {
            const int n = tid >> 1, h = tid & 1;
            u16* dp = d + (size_t)(n0 + n) * K + k0 + h * 64;
            #pragma unroll
            for (int c = 0; c < 8; ++c) {
                u16x8 o;
                #pragma unroll
                for (int j = 0; j < 8; ++j)
                    o[j] = f2bf(tl[(size_t)(h * 64 + c * 8 + j) * 128 + n]);
                __builtin_nontemporal_store(o, (u16x8*)(dp + c * 8));
            }
        }
        return;
    }

    // router path
    const int wav = tid >> 6, lane = tid & 63;
    const int t = id * 4 + wav;
    const float* xt = x + (size_t)t * 1024;
    float acc[8] = {0.f,0.f,0.f,0.f,0.f,0.f,0.f,0.f};
    #pragma unroll
    for (int c = 0; c < 4; c++) {
        const int base = c * 256 + lane * 4;
        const float4 xv = *(const float4*)(xt + base);
        ushort4 pk;
        pk.x = f2bf(xv.x); pk.y = f2bf(xv.y); pk.z = f2bf(xv.z); pk.w = f2bf(xv.w);
        *(ushort4*)(xb + (size_t)t * 1024 + base) = pk;
        #pragma unroll
        for (int e = 0; e < 8; e++) {
            const float4 wv = *(const float4*)(rw + e * 1024 + base);
            acc[e] += xv.x * wv.x + xv.y * wv.y + xv.z * wv.z + xv.w * wv.w;
        }
    }
    #pragma unroll
    for (int e = 0; e < 8; e++) {
        #pragma unroll
        for (int s = 32; s; s >>= 1) acc[e] += __shfl_xor(acc[e], s);
    }
    if (lane == 0) {
        float v0 = -3e38f, v1 = -3e38f; int i0 = 0, i1 = 0;
        #pragma unroll
        for (int e = 0; e < 8; e++) {
            const float l = acc[e] + rb[e];
            if (l > v0) { v1 = v0; i1 = i0; v0 = l; i0 = e; }
            else if (l > v1) { v1 = l; i1 = e; }
        }
        const float w0 = 1.0f / (1.0f + expf(v1 - v0));
        eidx[2 * t] = i0; eidx[2 * t + 1] = i1;
        wgt[2 * t] = w0; wgt[2 * t + 1] = 1.0f - w0;
        atomicAdd(&counts[i0], 1); atomicAdd(&counts[i1], 1);
    }
}

// ---------------- K2: place (prefix computed locally from counts; block 0 publishes offsets) ----------------
__global__ __launch_bounds__(256) void k_place2(
    const int* __restrict__ eidx, const int* __restrict__ counts, int* __restrict__ cursors,
    int* __restrict__ offsets, int* __restrict__ rows, int* __restrict__ pos_of)
{
    int base[8];
    int s = 0;
    #pragma unroll
    for (int e = 0; e < 8; e++) { base[e] = s; s += counts[e]; }
    if (blockIdx.x == 0 && threadIdx.x == 0) {
        #pragma unroll
        for (int e = 0; e < 8; e++) offsets[e] = base[e];
        offsets[8] = s;
    }
    const int a = blockIdx.x * 256 + threadIdx.x;   // 8192 assignments
    const int e = eidx[a];
    const int pos = base[e] + atomicAdd(&cursors[e], 1);
    rows[pos] = a >> 1;
    pos_of[a] = pos;
}

// shared GEMM macros: LDS [2][128][32] bf16 per operand, linear dest;
// source column pre-swizzled (chunk ^= (row>>1)&3), read offset swizzled to match.
#define STAGE_T(b, k0) { \
    char* ad = (char*)At + (b) * 8192 + wav * 1024; \
    char* bd = (char*)Bt + (b) * 8192 + wav * 1024; \
    GLD16(a_src0 + (k0), ad); \
    GLD16(a_src1 + (k0), ad + 4096); \
    GLD16(b_src0 + (k0), bd); \
    GLD16(b_src1 + (k0), bd + 4096); }

#define COMPUTE_T(b) { \
    const u16* Abp = Ab + (b) * 4096; \
    const u16* Bbp = Bb + (b) * 4096; \
    s16x8 af[4], bfr[4]; \
    _Pragma("unroll") \
    for (int i = 0; i < 4; i++) { \
        af[i]  = *(const s16x8*)(Abp + i * 512); \
        bfr[i] = *(const s16x8*)(Bbp + i * 512); \
    } \
    __builtin_amdgcn_s_setprio(1); \
    _Pragma("unroll") \
    for (int mi = 0; mi < 4; mi++) \
        _Pragma("unroll") \
        for (int ni = 0; ni < 4; ni++) \
            acc[mi][ni] = __builtin_amdgcn_mfma_f32_16x16x32_bf16(af[mi], bfr[ni], acc[mi][ni], 0, 0, 0); \
    __builtin_amdgcn_s_setprio(0); }

// ---------------- K5: grouped GEMM1 + bias + fast GELU -> h (bf16) ----------------
// 8192 blocks flat; swz -> (e, x=n-tile of 32, y=row-tile of 32, y fastest)
__global__ __launch_bounds__(256, 4) void k_gemm1(
    const u16* __restrict__ xb, const u16* __restrict__ W1t, const float* __restrict__ b1,
    u16* __restrict__ hbuf, const int* __restrict__ rows, const int* __restrict__ offsets)
{
    const int fid = blockIdx.x;
    const int swz = (fid & 7) * 1024 + (fid >> 3);   // bijective, nwg=8192
    const int y = swz & 31, xx = (swz >> 5) & 31, e = swz >> 10;

    const int off = offsets[e], cnt = offsets[e + 1] - off;
    const int row0 = y * 128;
    if (row0 >= cnt) return;
    const int n0 = xx * 128;
    const int tid = threadIdx.x;
    const int lane = tid & 63, wav = tid >> 6, lane15 = lane & 15;

    __shared__ u16 At[2][128][32];
    __shared__ u16 Bt[2][128][32];

    const int ar0 = tid >> 2;
    const int cl8 = (((tid & 3) ^ ((tid >> 3) & 3))) * 8;   // swizzled source chunk
    const int t0 = rows[off + min(row0 + ar0, cnt - 1)];
    const int t1 = rows[off + min(row0 + ar0 + 64, cnt - 1)];
    const u16* a_src0 = xb + (size_t)t0 * 1024 + cl8;
    const u16* a_src1 = xb + (size_t)t1 * 1024 + cl8;
    const u16* b_src0 = W1t + ((size_t)e * 4096 + n0 + ar0) * 1024 + cl8;
    const u16* b_src1 = b_src0 + (size_t)64 * 1024;

    f32x4 acc[4][4] = {};
    const int wr = wav >> 1, wc = wav & 1;
    const int koff = ((lane >> 4) ^ ((lane >> 1) & 3)) * 8;  // swizzled read chunk
    const u16* Ab = &At[0][wr * 64 + lane15][koff];
    const u16* Bb = &Bt[0][wc * 64 + lane15][koff];

    STAGE_T(0, 0);
    int b = 0;
    for (int k0 = 32; k0 < 1024; k0 += 32) {
        STAGE_T(b ^ 1, k0);
        VMCNT4;             // current buffer's 4 loads landed (next 4 stay in flight)
        BAR;
        COMPUTE_T(b);
        BAR;                // all waves done reading buffer b
        b ^= 1;
    }
    VMCNT0;
    BAR;
    COMPUTE_T(b);

    const int rb4 = (lane >> 4) * 4;
    const int colbase = n0 + wc * 64 + lane15;
    float bias[4];
    #pragma unroll
    for (int ni = 0; ni < 4; ni++) bias[ni] = b1[e * 4096 + colbase + ni * 16];
    #pragma unroll
    for (int mi = 0; mi < 4; mi++) {
        #pragma unroll
        for (int j = 0; j < 4; j++) {
            const int lrow = wr * 64 + mi * 16 + rb4 + j;
            if (row0 + lrow < cnt) {
                const size_t gr = (size_t)(off + row0 + lrow);
                #pragma unroll
                for (int ni = 0; ni < 4; ni++) {
                    const float v = acc[mi][ni][j] + bias[ni];
                    hbuf[gr * 4096 + colbase + ni * 16] = f2bf(gelu_f(v));
                }
            }
        }
    }
}

// ---------------- K6: grouped GEMM2 (split-K x4) + bias -> yb[4] (bf16) ----------------
// 8192 blocks flat; swz -> (z = e*4+kq, x=n-tile of 8, y=row-tile of 32, y fastest)
__global__ __launch_bounds__(256, 4) void k_gemm2(
    const u16* __restrict__ hbuf, const u16* __restrict__ W2t, const float* __restrict__ b2,
    u16* __restrict__ yb, const int* __restrict__ offsets)
{
    const int fid = blockIdx.x;
    const int swz = (fid & 7) * 1024 + (fid >> 3);   // bijective, nwg=8192
    const int y = swz & 31, xx = (swz >> 5) & 7, z = swz >> 8;
    const int e = z >> 2, kq = z & 3;

    const int off = offsets[e], cnt = offsets[e + 1] - off;
    const int row0 = y * 128;
    if (row0 >= cnt) return;
    const int n0 = xx * 128;
    const int tid = threadIdx.x;
    const int lane = tid & 63, wav = tid >> 6, lane15 = lane & 15;
    const int kbase = kq * 1024;

    __shared__ u16 At[2][128][32];
    __shared__ u16 Bt[2][128][32];

    const int ar0 = tid >> 2;
    const int cl8 = (((tid & 3) ^ ((tid >> 3) & 3))) * 8;
    const u16* a_src0 = hbuf + (size_t)(off + min(row0 + ar0, cnt - 1)) * 4096 + kbase + cl8;
    const u16* a_src1 = hbuf + (size_t)(off + min(row0 + ar0 + 64, cnt - 1)) * 4096 + kbase + cl8;
    const u16* b_src0 = W2t + ((size_t)e * 1024 + n0 + ar0) * 4096 + kbase + cl8;
    const u16* b_src1 = b_src0 + (size_t)64 * 4096;

    f32x4 acc[4][4] = {};
    const int wr = wav >> 1, wc = wav & 1;
    const int koff = ((lane >> 4) ^ ((lane >> 1) & 3)) * 8;
    const u16* Ab = &At[0][wr * 64 + lane15][koff];
    const u16* Bb = &Bt[0][wc * 64 + lane15][koff];

    STAGE_T(0, 0);
    int b = 0;
    for (int k0 = 32; k0 < 1024; k0 += 32) {
        STAGE_T(b ^ 1, k0);
        VMCNT4;
        BAR;
        COMPUTE_T(b);
        BAR;
        b ^= 1;
    }
    VMCNT0;
    BAR;
    COMPUTE_T(b);

    u16* yy = yb + (size_t)kq * 8192 * 1024;
    const int rb4 = (lane >> 4) * 4;
    const int colbase = n0 + wc * 64 + lane15;
    float bias[4];
    #pragma unroll
    for (int ni = 0; ni < 4; ni++) bias[ni] = (kq == 0) ? b2[e * 1024 + colbase + ni * 16] : 0.f;
    #pragma unroll
    for (int mi = 0; mi < 4; mi++) {
        #pragma unroll
        for (int j = 0; j < 4; j++) {
            const int lrow = wr * 64 + mi * 16 + rb4 + j;
            if (row0 + lrow < cnt) {
                const size_t gr = (size_t)(off + row0 + lrow);
                #pragma unroll
                for (int ni = 0; ni < 4; ni++)
                    yy[gr * 1024 + colbase + ni * 16] = f2bf(acc[mi][ni][j] + bias[ni]);
            }
        }
    }
}

// ---------------- K7: combine (w0*sum4(y[p0]) + w1*sum4(y[p1]) + residual) + LayerNorm ----------------
__global__ __launch_bounds__(256) void k_combine(
    const float* __restrict__ x, const u16* __restrict__ yb,
    const int* __restrict__ pos_of, const float* __restrict__ wgt,
    const float* __restrict__ gamma, const float* __restrict__ beta,
    float* __restrict__ out)
{
    const int t = blockIdx.x;
    const int tid = threadIdx.x;
    const int p0 = pos_of[2 * t], p1 = pos_of[2 * t + 1];
    const float w0 = wgt[2 * t], w1 = wgt[2 * t + 1];
    const int j4 = tid * 4;
    const float4 xv = *(const float4*)(x + (size_t)t * 1024 + j4);
    float s0[4] = {0.f, 0.f, 0.f, 0.f};
    float s1[4] = {0.f, 0.f, 0.f, 0.f};
    #pragma unroll
    for (int kq = 0; kq < 4; kq++) {
        const u16* ybq = yb + (size_t)kq * 8192 * 1024;
        const ushort4 u0 = *(const ushort4*)(ybq + (size_t)p0 * 1024 + j4);
        const ushort4 u1 = *(const ushort4*)(ybq + (size_t)p1 * 1024 + j4);
        s0[0] += bf2f(u0.x); s0[1] += bf2f(u0.y); s0[2] += bf2f(u0.z); s0[3] += bf2f(u0.w);
        s1[0] += bf2f(u1.x); s1[1] += bf2f(u1.y); s1[2] += bf2f(u1.z); s1[3] += bf2f(u1.w);
    }
    float a0 = xv.x + w0 * s0[0] + w1 * s1[0];
    float a1 = xv.y + w0 * s0[1] + w1 * s1[1];
    float a2 = xv.z + w0 * s0[2] + w1 * s1[2];
    float a3 = xv.w + w0 * s0[3] + w1 * s1[3];
    float s = a0 + a1 + a2 + a3;
    float q = a0 * a0 + a1 * a1 + a2 * a2 + a3 * a3;
    #pragma unroll
    for (int o = 32; o; o >>= 1) { s += __shfl_xor(s, o); q += __shfl_xor(q, o); }
    __shared__ float ls[4], lq[4];
    const int wav = tid >> 6, lane = tid & 63;
    if (lane == 0) { ls[wav] = s; lq[wav] = q; }
    __syncthreads();
    s = ls[0] + ls[1] + ls[2] + ls[3];
    q = lq[0] + lq[1] + lq[2] + lq[3];
    const float mu = s * (1.0f / 1024.0f);
    const float var = q * (1.0f / 1024.0f) - mu * mu;
    const float rs = rsqrtf(var + 1e-5f);
    const float4 g = *(const float4*)(gamma + j4);
    const float4 b = *(const float4*)(beta + j4);
    float4 o4;
    o4.x = (a0 - mu) * rs * g.x + b.x;
    o4.y = (a1 - mu) * rs * g.y + b.y;
    o4.z = (a2 - mu) * rs * g.z + b.z;
    o4.w = (a3 - mu) * rs * g.w + b.w;
    *(float4*)(out + (size_t)t * 1024 + j4) = o4;
}

extern "C" void kernel_launch(void* const* d_in, const int* in_sizes, int n_in,
                              void* d_out, int out_size, void* d_ws, size_t ws_size,
                              hipStream_t stream) {
    const float* x     = (const float*)d_in[0];   // [2,2048,1024]
    const float* rw    = (const float*)d_in[1];   // [8,1024]
    const float* rb    = (const float*)d_in[2];   // [8]
    const float* W1    = (const float*)d_in[3];   // [8,1024,4096]
    const float* b1    = (const float*)d_in[4];   // [8,4096]
    const float* W2    = (const float*)d_in[5];   // [8,4096,1024]
    const float* b2    = (const float*)d_in[6];   // [8,1024]
    const float* gamma = (const float*)d_in[7];   // [1024]
    const float* beta  = (const float*)d_in[8];   // [1024]
    float* out = (float*)d_out;

    // workspace carve (256B aligned)
    char* p = (char*)d_ws;
    auto alloc = [&](size_t bytes) { char* r = p; p += (bytes + 255) & ~(size_t)255; return r; };
    int*   counts  = (int*)alloc(16 * sizeof(int));      // counts[0..7], cursors[8..15]
    int*   cursors = counts + 8;
    int*   offsets = (int*)alloc(9 * sizeof(int));
    int*   eidx    = (int*)alloc(8192 * sizeof(int));
    float* wgt     = (float*)alloc(8192 * sizeof(float));
    int*   pos_of  = (int*)alloc(8192 * sizeof(int));
    int*   rows    = (int*)alloc(8192 * sizeof(int));
    u16*   xb      = (u16*)alloc((size_t)4096 * 1024 * 2);
    u16*   W1t     = (u16*)alloc((size_t)8 * 4096 * 1024 * 2);   // 64MB (dead after gemm1)
    u16*   W2t     = (u16*)alloc((size_t)8 * 1024 * 4096 * 2);
    u16*   hbuf    = (u16*)alloc((size_t)8192 * 4096 * 2);
    // yb = 4 bf16 partial buffers (4 x 16MB = 64MB) alias W1t (dead after gemm1)
    u16* yb = W1t;

    hipLaunchKernelGGL(k_init, dim3(1), dim3(64), 0, stream, counts);
    hipLaunchKernelGGL(k_pre, dim3(5120), dim3(256), 0, stream,
                       x, rw, rb, xb, eidx, wgt, counts, W1, W1t, W2, W2t);
    hipLaunchKernelGGL(k_place2, dim3(32), dim3(256), 0, stream,
                       eidx, counts, cursors, offsets, rows, pos_of);
    hipLaunchKernelGGL(k_gemm1, dim3(8192), dim3(256), 0, stream, xb, W1t, b1, hbuf, rows, offsets);
    hipLaunchKernelGGL(k_gemm2, dim3(8192), dim3(256), 0, stream, hbuf, W2t, b2, yb, offsets);
    hipLaunchKernelGGL(k_combine, dim3(4096), dim3(256), 0, stream, x, yb, pos_of, wgt, gamma, beta, out);
}

// Round 20
// 407.464 us; speedup vs baseline: 1.6704x; 1.6704x over previous
//
#include <hip/hip_runtime.h>
#include <hip/hip_bf16.h>

// MoE head: router(top2 of 8) -> compact -> GEMM1+GELU -> GEMM2(split-K x4) -> combine+residual+LN
// R20: R13 base (best, 423us) + NONTEMPORAL LOADS ONLY in the transpose (R18 A/B isolation:
//      NT loads gave k_pre 195->170; NT stores gave the gain back via cold GEMM B-reads).
//      Stores stay cached so W1t/W2t are L2/L3-resident for the GEMMs. Everything else = R13.

typedef unsigned short u16;
typedef unsigned int u32;
typedef __attribute__((ext_vector_type(4))) float f32x4;
typedef __attribute__((ext_vector_type(8))) short s16x8;
typedef __attribute__((ext_vector_type(4))) unsigned short u16x4;
typedef __attribute__((ext_vector_type(8))) unsigned short u16x8;

#define GLD16(gp, lp) __builtin_amdgcn_global_load_lds( \
    (const __attribute__((address_space(1))) void*)(gp), \
    (__attribute__((address_space(3))) void*)(lp), 16, 0, 0)

__device__ __forceinline__ u16 f2bf(float f) {
    union { float f; u32 u; } v; v.f = f;
    u32 u = v.u;
    return (u16)((u + 0x7fffu + ((u >> 16) & 1u)) >> 16);
}
__device__ __forceinline__ float bf2f(u16 h) {
    union { u32 u; float f; } v; v.u = ((u32)h) << 16; return v.f;
}

// fast GELU: v * sigmoid(1.59577v + 0.0713548v^3)
__device__ __forceinline__ float gelu_f(float v) {
    const float u = v * (0.7978845608f + 0.0356774081f * v * v);
    const float t = __expf(-2.0f * u);
    return v * __builtin_amdgcn_rcpf(1.0f + t);
}

// ---------------- K0: zero counts+cursors (16 ints) ----------------
__global__ void k_init(int* cc) { if (threadIdx.x < 16) cc[threadIdx.x] = 0; }

// ---------------- K1: fused router + W1/W2 transpose-convert (5120 blocks) ----------------
// blocks 0..1023: router; 1024..3071: W1 tiles; 3072..5119: W2 tiles.
// transp: SRC [K][N] f32 -> DST [N][K] bf16, 128k x 128n per block.
// NT loads (weights never re-read); REGULAR stores (W1t/W2t stay cache-resident for GEMMs).
__global__ __launch_bounds__(256) void k_pre(
    const float* __restrict__ x, const float* __restrict__ rw, const float* __restrict__ rb,
    u16* __restrict__ xb, int* __restrict__ eidx, float* __restrict__ wgt, int* __restrict__ counts,
    const float* __restrict__ W1, u16* __restrict__ W1t,
    const float* __restrict__ W2, u16* __restrict__ W2t)
{
    __shared__ u16 tl[128 * 128];   // 32KB, transpose tiles only
    const int id = blockIdx.x;
    const int tid = threadIdx.x;

    if (id >= 1024) {
        const float* s; u16* d; int K, N, k0, n0;
        if (id < 3072) {
            const int id2 = id - 1024;          // W1: 256 tiles/e (8 kt x 32 nt)
            const int e = id2 >> 8, rem = id2 & 255;
            K = 1024; N = 4096;
            k0 = (rem >> 5) * 128; n0 = (rem & 31) * 128;
            s = W1 + (size_t)e * 1024 * 4096; d = W1t + (size_t)e * 1024 * 4096;
        } else {
            const int id3 = id - 3072;          // W2: 256 tiles/e (32 kt x 8 nt)
            const int e = id3 >> 8, rem = id3 & 255;
            K = 4096; N = 1024;
            k0 = (rem >> 3) * 128; n0 = (rem & 7) * 128;
            s = W2 + (size_t)e * 4096 * 1024; d = W2t + (size_t)e * 1024 * 4096;
        }

        // READ: 4x4 register transpose -> swizzled b64 LDS writes (NT global loads)
        const int nq = (tid & 31) * 4;      // 4 n per thread
        const int kb = (tid >> 5) * 4;      // 8 parallel k-slabs
        #pragma unroll
        for (int iter = 0; iter < 4; ++iter) {
            const int k = iter * 32 + kb;
            const f32x4 r0 = __builtin_nontemporal_load((const f32x4*)(s + (size_t)(k0 + k    ) * N + n0 + nq));
            const f32x4 r1 = __builtin_nontemporal_load((const f32x4*)(s + (size_t)(k0 + k + 1) * N + n0 + nq));
            const f32x4 r2 = __builtin_nontemporal_load((const f32x4*)(s + (size_t)(k0 + k + 2) * N + n0 + nq));
            const f32x4 r3 = __builtin_nontemporal_load((const f32x4*)(s + (size_t)(k0 + k + 3) * N + n0 + nq));
            const int c16 = k >> 3, half = (k >> 2) & 1;
            const float rrr[4][4] = {{r0[0],r1[0],r2[0],r3[0]},{r0[1],r1[1],r2[1],r3[1]},
                                     {r0[2],r1[2],r2[2],r3[2]},{r0[3],r1[3],r2[3],r3[3]}};
            #pragma unroll
            for (int i = 0; i < 4; ++i) {
                const int n = nq + i;
                const int c16s = c16 ^ (n & 15) ^ (((n >> 4) & 3) << 2);
                u16x4 p;
                p[0] = f2bf(rrr[i][0]); p[1] = f2bf(rrr[i][1]);
                p[2] = f2bf(rrr[i][2]); p[3] = f2bf(rrr[i][3]);
                *(u16x4*)(&tl[n * 128 + c16s * 8 + half * 4]) = p;
            }
        }
        __syncthreads();
        // WRITE: b128 LDS reads -> regular 16B stores, 8-lane x 128B groups
        #pragma unroll
        for (int rr2 = 0; rr2 < 4; ++rr2) {
            const int n = rr2 * 32 + (tid >> 3);
            #pragma unroll
            for (int ci = 0; ci < 2; ++ci) {
                const int c16 = ci * 8 + (tid & 7);
                const int c16s = c16 ^ (n & 15) ^ (((n >> 4) & 3) << 2);
                const u16x8 v = *(const u16x8*)(&tl[n * 128 + c16s * 8]);
                *(u16x8*)(d + (size_t)(n0 + n) * K + k0 + c16 * 8) = v;
            }
        }
        return;
    }

    // router path
    const int wav = tid >> 6, lane = tid & 63;
    const int t = id * 4 + wav;
    const float* xt = x + (size_t)t * 1024;
    float acc[8] = {0.f,0.f,0.f,0.f,0.f,0.f,0.f,0.f};
    #pragma unroll
    for (int c = 0; c < 4; c++) {
        const int base = c * 256 + lane * 4;
        const float4 xv = *(const float4*)(xt + base);
        ushort4 pk;
        pk.x = f2bf(xv.x); pk.y = f2bf(xv.y); pk.z = f2bf(xv.z); pk.w = f2bf(xv.w);
        *(ushort4*)(xb + (size_t)t * 1024 + base) = pk;
        #pragma unroll
        for (int e = 0; e < 8; e++) {
            const float4 wv = *(const float4*)(rw + e * 1024 + base);
            acc[e] += xv.x * wv.x + xv.y * wv.y + xv.z * wv.z + xv.w * wv.w;
        }
    }
    #pragma unroll
    for (int e = 0; e < 8; e++) {
        #pragma unroll
        for (int s = 32; s; s >>= 1) acc[e] += __shfl_xor(acc[e], s);
    }
    if (lane == 0) {
        float v0 = -3e38f, v1 = -3e38f; int i0 = 0, i1 = 0;
        #pragma unroll
        for (int e = 0; e < 8; e++) {
            const float l = acc[e] + rb[e];
            if (l > v0) { v1 = v0; i1 = i0; v0 = l; i0 = e; }
            else if (l > v1) { v1 = l; i1 = e; }
        }
        const float w0 = 1.0f / (1.0f + expf(v1 - v0));
        eidx[2 * t] = i0; eidx[2 * t + 1] = i1;
        wgt[2 * t] = w0; wgt[2 * t + 1] = 1.0f - w0;
        atomicAdd(&counts[i0], 1); atomicAdd(&counts[i1], 1);
    }
}

// ---------------- K2: place (prefix computed locally from counts; block 0 publishes offsets) ----------------
__global__ __launch_bounds__(256) void k_place2(
    const int* __restrict__ eidx, const int* __restrict__ counts, int* __restrict__ cursors,
    int* __restrict__ offsets, int* __restrict__ rows, int* __restrict__ pos_of)
{
    int base[8];
    int s = 0;
    #pragma unroll
    for (int e = 0; e < 8; e++) { base[e] = s; s += counts[e]; }
    if (blockIdx.x == 0 && threadIdx.x == 0) {
        #pragma unroll
        for (int e = 0; e < 8; e++) offsets[e] = base[e];
        offsets[8] = s;
    }
    const int a = blockIdx.x * 256 + threadIdx.x;   // 8192 assignments
    const int e = eidx[a];
    const int pos = base[e] + atomicAdd(&cursors[e], 1);
    rows[pos] = a >> 1;
    pos_of[a] = pos;
}

// shared GEMM macros: LDS [2][128][32] bf16 per operand, linear dest;
// source column pre-swizzled (chunk ^= (row>>1)&3), read offset swizzled to match.
#define STAGE_T(b, k0) { \
    char* ad = (char*)At + (b) * 8192 + wav * 1024; \
    char* bd = (char*)Bt + (b) * 8192 + wav * 1024; \
    GLD16(a_src0 + (k0), ad); \
    GLD16(a_src1 + (k0), ad + 4096); \
    GLD16(b_src0 + (k0), bd); \
    GLD16(b_src1 + (k0), bd + 4096); }

#define COMPUTE_T(b) { \
    const u16* Abp = Ab + (b) * 4096; \
    const u16* Bbp = Bb + (b) * 4096; \
    s16x8 af[4], bfr[4]; \
    _Pragma("unroll") \
    for (int i = 0; i < 4; i++) { \
        af[i]  = *(const s16x8*)(Abp + i * 512); \
        bfr[i] = *(const s16x8*)(Bbp + i * 512); \
    } \
    __builtin_amdgcn_s_setprio(1); \
    _Pragma("unroll") \
    for (int mi = 0; mi < 4; mi++) \
        _Pragma("unroll") \
        for (int ni = 0; ni < 4; ni++) \
            acc[mi][ni] = __builtin_amdgcn_mfma_f32_16x16x32_bf16(af[mi], bfr[ni], acc[mi][ni], 0, 0, 0); \
    __builtin_amdgcn_s_setprio(0); }

#define VMCNT4 asm volatile("s_waitcnt vmcnt(4)" ::: "memory")
#define VMCNT0 asm volatile("s_waitcnt vmcnt(0)" ::: "memory")
#define BAR __builtin_amdgcn_s_barrier()

// ---------------- K5: grouped GEMM1 + bias + fast GELU -> h (bf16) ----------------
// 8192 blocks flat; swz -> (e, x=n-tile of 32, y=row-tile of 32, y fastest)
__global__ __launch_bounds__(256, 4) void k_gemm1(
    const u16* __restrict__ xb, const u16* __restrict__ W1t, const float* __restrict__ b1,
    u16* __restrict__ hbuf, const int* __restrict__ rows, const int* __restrict__ offsets)
{
    const int fid = blockIdx.x;
    const int swz = (fid & 7) * 1024 + (fid >> 3);   // bijective, nwg=8192
    const int y = swz & 31, xx = (swz >> 5) & 31, e = swz >> 10;

    const int off = offsets[e], cnt = offsets[e + 1] - off;
    const int row0 = y * 128;
    if (row0 >= cnt) return;
    const int n0 = xx * 128;
    const int tid = threadIdx.x;
    const int lane = tid & 63, wav = tid >> 6, lane15 = lane & 15;

    __shared__ u16 At[2][128][32];
    __shared__ u16 Bt[2][128][32];

    const int ar0 = tid >> 2;
    const int cl8 = (((tid & 3) ^ ((tid >> 3) & 3))) * 8;   // swizzled source chunk
    const int t0 = rows[off + min(row0 + ar0, cnt - 1)];
    const int t1 = rows[off + min(row0 + ar0 + 64, cnt - 1)];
    const u16* a_src0 = xb + (size_t)t0 * 1024 + cl8;
    const u16* a_src1 = xb + (size_t)t1 * 1024 + cl8;
    const u16* b_src0 = W1t + ((size_t)e * 4096 + n0 + ar0) * 1024 + cl8;
    const u16* b_src1 = b_src0 + (size_t)64 * 1024;

    f32x4 acc[4][4] = {};
    const int wr = wav >> 1, wc = wav & 1;
    const int koff = ((lane >> 4) ^ ((lane >> 1) & 3)) * 8;  // swizzled read chunk
    const u16* Ab = &At[0][wr * 64 + lane15][koff];
    const u16* Bb = &Bt[0][wc * 64 + lane15][koff];

    STAGE_T(0, 0);
    int b = 0;
    for (int k0 = 32; k0 < 1024; k0 += 32) {
        STAGE_T(b ^ 1, k0);
        VMCNT4;             // current buffer's 4 loads landed (next 4 stay in flight)
        BAR;
        COMPUTE_T(b);
        BAR;                // all waves done reading buffer b
        b ^= 1;
    }
    VMCNT0;
    BAR;
    COMPUTE_T(b);

    const int rb4 = (lane >> 4) * 4;
    const int colbase = n0 + wc * 64 + lane15;
    float bias[4];
    #pragma unroll
    for (int ni = 0; ni < 4; ni++) bias[ni] = b1[e * 4096 + colbase + ni * 16];
    #pragma unroll
    for (int mi = 0; mi < 4; mi++) {
        #pragma unroll
        for (int j = 0; j < 4; j++) {
            const int lrow = wr * 64 + mi * 16 + rb4 + j;
            if (row0 + lrow < cnt) {
                const size_t gr = (size_t)(off + row0 + lrow);
                #pragma unroll
                for (int ni = 0; ni < 4; ni++) {
                    const float v = acc[mi][ni][j] + bias[ni];
                    hbuf[gr * 4096 + colbase + ni * 16] = f2bf(gelu_f(v));
                }
            }
        }
    }
}

// ---------------- K6: grouped GEMM2 (split-K x4) + bias -> yb[4] (bf16) ----------------
// 8192 blocks flat; swz -> (z = e*4+kq, x=n-tile of 8, y=row-tile of 32, y fastest)
__global__ __launch_bounds__(256, 4) void k_gemm2(
    const u16* __restrict__ hbuf, const u16* __restrict__ W2t, const float* __restrict__ b2,
    u16* __restrict__ yb, const int* __restrict__ offsets)
{
    const int fid = blockIdx.x;
    const int swz = (fid & 7) * 1024 + (fid >> 3);   // bijective, nwg=8192
    const int y = swz & 31, xx = (swz >> 5) & 7, z = swz >> 8;
    const int e = z >> 2, kq = z & 3;

    const int off = offsets[e], cnt = offsets[e + 1] - off;
    const int row0 = y * 128;
    if (row0 >= cnt) return;
    const int n0 = xx * 128;
    const int tid = threadIdx.x;
    const int lane = tid & 63, wav = tid >> 6, lane15 = lane & 15;
    const int kbase = kq * 1024;

    __shared__ u16 At[2][128][32];
    __shared__ u16 Bt[2][128][32];

    const int ar0 = tid >> 2;
    const int cl8 = (((tid & 3) ^ ((tid >> 3) & 3))) * 8;
    const u16* a_src0 = hbuf + (size_t)(off + min(row0 + ar0, cnt - 1)) * 4096 + kbase + cl8;
    const u16* a_src1 = hbuf + (size_t)(off + min(row0 + ar0 + 64, cnt - 1)) * 4096 + kbase + cl8;
    const u16* b_src0 = W2t + ((size_t)e * 1024 + n0 + ar0) * 4096 + kbase + cl8;
    const u16* b_src1 = b_src0 + (size_t)64 * 4096;

    f32x4 acc[4][4] = {};
    const int wr = wav >> 1, wc = wav & 1;
    const int koff = ((lane >> 4) ^ ((lane >> 1) & 3)) * 8;
    const u16* Ab = &At[0][wr * 64 + lane15][koff];
    const u16* Bb = &Bt[0][wc * 64 + lane15][koff];

    STAGE_T(0, 0);
    int b = 0;
    for (int k0 = 32; k0 < 1024; k0 += 32) {
        STAGE_T(b ^ 1, k0);
        VMCNT4;
        BAR;
        COMPUTE_T(b);
        BAR;
        b ^= 1;
    }
    VMCNT0;
    BAR;
    COMPUTE_T(b);

    u16* yy = yb + (size_t)kq * 8192 * 1024;
    const int rb4 = (lane >> 4) * 4;
    const int colbase = n0 + wc * 64 + lane15;
    float bias[4];
    #pragma unroll
    for (int ni = 0; ni < 4; ni++) bias[ni] = (kq == 0) ? b2[e * 1024 + colbase + ni * 16] : 0.f;
    #pragma unroll
    for (int mi = 0; mi < 4; mi++) {
        #pragma unroll
        for (int j = 0; j < 4; j++) {
            const int lrow = wr * 64 + mi * 16 + rb4 + j;
            if (row0 + lrow < cnt) {
                const size_t gr = (size_t)(off + row0 + lrow);
                #pragma unroll
                for (int ni = 0; ni < 4; ni++)
                    yy[gr * 1024 + colbase + ni * 16] = f2bf(acc[mi][ni][j] + bias[ni]);
            }
        }
    }
}

// ---------------- K7: combine (w0*sum4(y[p0]) + w1*sum4(y[p1]) + residual) + LayerNorm ----------------
__global__ __launch_bounds__(256) void k_combine(
    const float* __restrict__ x, const u16* __restrict__ yb,
    const int* __restrict__ pos_of, const float* __restrict__ wgt,
    const float* __restrict__ gamma, const float* __restrict__ beta,
    float* __restrict__ out)
{
    const int t = blockIdx.x;
    const int tid = threadIdx.x;
    const int p0 = pos_of[2 * t], p1 = pos_of[2 * t + 1];
    const float w0 = wgt[2 * t], w1 = wgt[2 * t + 1];
    const int j4 = tid * 4;
    const float4 xv = *(const float4*)(x + (size_t)t * 1024 + j4);
    float s0[4] = {0.f, 0.f, 0.f, 0.f};
    float s1[4] = {0.f, 0.f, 0.f, 0.f};
    #pragma unroll
    for (int kq = 0; kq < 4; kq++) {
        const u16* ybq = yb + (size_t)kq * 8192 * 1024;
        const ushort4 u0 = *(const ushort4*)(ybq + (size_t)p0 * 1024 + j4);
        const ushort4 u1 = *(const ushort4*)(ybq + (size_t)p1 * 1024 + j4);
        s0[0] += bf2f(u0.x); s0[1] += bf2f(u0.y); s0[2] += bf2f(u0.z); s0[3] += bf2f(u0.w);
        s1[0] += bf2f(u1.x); s1[1] += bf2f(u1.y); s1[2] += bf2f(u1.z); s1[3] += bf2f(u1.w);
    }
    float a0 = xv.x + w0 * s0[0] + w1 * s1[0];
    float a1 = xv.y + w0 * s0[1] + w1 * s1[1];
    float a2 = xv.z + w0 * s0[2] + w1 * s1[2];
    float a3 = xv.w + w0 * s0[3] + w1 * s1[3];
    float s = a0 + a1 + a2 + a3;
    float q = a0 * a0 + a1 * a1 + a2 * a2 + a3 * a3;
    #pragma unroll
    for (int o = 32; o; o >>= 1) { s += __shfl_xor(s, o); q += __shfl_xor(q, o); }
    __shared__ float ls[4], lq[4];
    const int wav = tid >> 6, lane = tid & 63;
    if (lane == 0) { ls[wav] = s; lq[wav] = q; }
    __syncthreads();
    s = ls[0] + ls[1] + ls[2] + ls[3];
    q = lq[0] + lq[1] + lq[2] + lq[3];
    const float mu = s * (1.0f / 1024.0f);
    const float var = q * (1.0f / 1024.0f) - mu * mu;
    const float rs = rsqrtf(var + 1e-5f);
    const float4 g = *(const float4*)(gamma + j4);
    const float4 b = *(const float4*)(beta + j4);
    float4 o4;
    o4.x = (a0 - mu) * rs * g.x + b.x;
    o4.y = (a1 - mu) * rs * g.y + b.y;
    o4.z = (a2 - mu) * rs * g.z + b.z;
    o4.w = (a3 - mu) * rs * g.w + b.w;
    *(float4*)(out + (size_t)t * 1024 + j4) = o4;
}

extern "C" void kernel_launch(void* const* d_in, const int* in_sizes, int n_in,
                              void* d_out, int out_size, void* d_ws, size_t ws_size,
                              hipStream_t stream) {
    const float* x     = (const float*)d_in[0];   // [2,2048,1024]
    const float* rw    = (const float*)d_in[1];   // [8,1024]
    const float* rb    = (const float*)d_in[2];   // [8]
    const float* W1    = (const float*)d_in[3];   // [8,1024,4096]
    const float* b1    = (const float*)d_in[4];   // [8,4096]
    const float* W2    = (const float*)d_in[5];   // [8,4096,1024]
    const float* b2    = (const float*)d_in[6];   // [8,1024]
    const float* gamma = (const float*)d_in[7];   // [1024]
    const float* beta  = (const float*)d_in[8];   // [1024]
    float* out = (float*)d_out;

    // workspace carve (256B aligned)
    char* p = (char*)d_ws;
    auto alloc = [&](size_t bytes) { char* r = p; p += (bytes + 255) & ~(size_t)255; return r; };
    int*   counts  = (int*)alloc(16 * sizeof(int));      // counts[0..7], cursors[8..15]
    int*   cursors = counts + 8;
    int*   offsets = (int*)alloc(9 * sizeof(int));
    int*   eidx    = (int*)alloc(8192 * sizeof(int));
    float* wgt     = (float*)alloc(8192 * sizeof(float));
    int*   pos_of  = (int*)alloc(8192 * sizeof(int));
    int*   rows    = (int*)alloc(8192 * sizeof(int));
    u16*   xb      = (u16*)alloc((size_t)4096 * 1024 * 2);
    u16*   W1t     = (u16*)alloc((size_t)8 * 4096 * 1024 * 2);   // 64MB (dead after gemm1)
    u16*   W2t     = (u16*)alloc((size_t)8 * 1024 * 4096 * 2);
    u16*   hbuf    = (u16*)alloc((size_t)8192 * 4096 * 2);
    // yb = 4 bf16 partial buffers (4 x 16MB = 64MB) alias W1t (dead after gemm1)
    u16* yb = W1t;

    hipLaunchKernelGGL(k_init, dim3(1), dim3(64), 0, stream, counts);
    hipLaunchKernelGGL(k_pre, dim3(5120), dim3(256), 0, stream,
                       x, rw, rb, xb, eidx, wgt, counts, W1, W1t, W2, W2t);
    hipLaunchKernelGGL(k_place2, dim3(32), dim3(256), 0, stream,
                       eidx, counts, cursors, offsets, rows, pos_of);
    hipLaunchKernelGGL(k_gemm1, dim3(8192), dim3(256), 0, stream, xb, W1t, b1, hbuf, rows, offsets);
    hipLaunchKernelGGL(k_gemm2, dim3(8192), dim3(256), 0, stream, hbuf, W2t, b2, yb, offsets);
    hipLaunchKernelGGL(k_combine, dim3(4096), dim3(256), 0, stream, x, yb, pos_of, wgt, gamma, beta, out);
}